// Round 14
// baseline (114.798 us; speedup 1.0000x reference)
//
#include <hip/hip_runtime.h>
#include <math.h>

#define S_NEI 32

// ---------------- transpose 256x256 (WkT[e][f] = Wk[f][e]) ----------------
__global__ __launch_bounds__(256) void transpose256(const float* __restrict__ in,
                                                    float* __restrict__ outT) {
    __shared__ float tile[32][33];
    const int bx = blockIdx.x * 32, by = blockIdx.y * 32;
    const int x = threadIdx.x, y = threadIdx.y;  // 32 x 8
#pragma unroll
    for (int i = 0; i < 32; i += 8)
        tile[y + i][x] = in[(by + y + i) * 256 + bx + x];
    __syncthreads();
#pragma unroll
    for (int i = 0; i < 32; i += 8)
        outT[(bx + y + i) * 256 + by + x] = tile[x][y + i];
}

// ---------------- legacy 8x256 tile GEMM (for tiny precompute GEMMs) -------
template <int KT>
__device__ __forceinline__ void gemm_tile8(const float* __restrict__ A, int row0,
                                           const float* __restrict__ B,
                                           float acc[2][4], float* __restrict__ sA,
                                           float* __restrict__ sB) {
    const int t = threadIdx.x;
    const int tr = t >> 6, tc = t & 63;
    const int r = t >> 5;
    const int k1 = t & 31;
    const size_t arow = (size_t)(row0 + r) * KT;
    for (int kb = 0; kb < KT; kb += 32) {
        sA[k1 * 12 + r] = A[arow + kb + k1];
#pragma unroll
        for (int i = 0; i < 8; ++i) {
            *reinterpret_cast<float4*>(&sB[(i * 4 + tr) * 256 + tc * 4]) =
                *reinterpret_cast<const float4*>(&B[(size_t)(kb + i * 4 + tr) * 256 + tc * 4]);
        }
        __syncthreads();
#pragma unroll
        for (int k = 0; k < 32; ++k) {
            const float2 a2 = *reinterpret_cast<const float2*>(&sA[k * 12 + tr * 2]);
            const float4 b4 = *reinterpret_cast<const float4*>(&sB[k * 256 + tc * 4]);
            acc[0][0] += a2.x * b4.x; acc[0][1] += a2.x * b4.y;
            acc[0][2] += a2.x * b4.z; acc[0][3] += a2.x * b4.w;
            acc[1][0] += a2.y * b4.x; acc[1][1] += a2.y * b4.y;
            acc[1][2] += a2.y * b4.z; acc[1][3] += a2.y * b4.w;
        }
        __syncthreads();
    }
}

// Wqk=Wq@WkT, Wvc=Wv@Wc_top, Wmc=Wm@Wc_bot
__global__ __launch_bounds__(256) void precompute3(const float* __restrict__ Wq,
                                                   const float* __restrict__ Wv,
                                                   const float* __restrict__ Wm,
                                                   const float* __restrict__ Wc,
                                                   const float* __restrict__ WkT,
                                                   float* __restrict__ Wqk,
                                                   float* __restrict__ Wvc,
                                                   float* __restrict__ Wmc) {
    __shared__ float sA[32 * 12];
    __shared__ float sB[32 * 256];
    float acc[2][4] = {};
    const float *Ap, *Bp;
    float* Cp;
    switch (blockIdx.y) {
        case 0: Ap = Wq; Bp = WkT; Cp = Wqk; break;
        case 1: Ap = Wv; Bp = Wc; Cp = Wvc; break;
        default: Ap = Wm; Bp = Wc + 256 * 256; Cp = Wmc; break;
    }
    const int row0 = blockIdx.x * 8;
    gemm_tile8<256>(Ap, row0, Bp, acc, sA, sB);
    const int tr = threadIdx.x >> 6, tc = threadIdx.x & 63;
#pragma unroll
    for (int i = 0; i < 2; ++i) {
        float4 v = make_float4(acc[i][0], acc[i][1], acc[i][2], acc[i][3]);
        *reinterpret_cast<float4*>(&Cp[(row0 + tr * 2 + i) * 256 + tc * 4]) = v;
    }
}

// bqk = bq@WkT ; bfull = bv@Wc_top + bm@Wc_bot + bc  (block per column)
__global__ __launch_bounds__(256) void bias_k(const float* __restrict__ bq,
                                              const float* __restrict__ bv,
                                              const float* __restrict__ bm,
                                              const float* __restrict__ bc,
                                              const float* __restrict__ Wc,
                                              const float* __restrict__ WkT,
                                              float* __restrict__ bqk,
                                              float* __restrict__ bfull) {
    const int c = blockIdx.x;
    const int e = threadIdx.x;
    const int w = e >> 6, l = e & 63;
    float a = bq[e] * WkT[e * 256 + c];
    float v = bv[e] * Wc[e * 256 + c] + bm[e] * Wc[(256 + e) * 256 + c];
    __shared__ float redA[4], redV[4];
#pragma unroll
    for (int off = 32; off; off >>= 1) { a += __shfl_xor(a, off); v += __shfl_xor(v, off); }
    if (l == 0) { redA[w] = a; redV[w] = v; }
    __syncthreads();
    if (e == 0) {
        bqk[c] = redA[0] + redA[1] + redA[2] + redA[3];
        bfull[c] = bc[c] + redV[0] + redV[1] + redV[2] + redV[3];
    }
}

// ---------------- lean 8-row x 256-col K=256 GEMM body ---------------------
// 256 thr / 4 waves; wave w owns rows {2w, 2w+1}; lane owns 4 cols.
// A staged transposed in LDS (stride 10 words: reads are wave-uniform
// broadcasts, 8B-aligned; staging writes 2-way conflict = free).
// B streamed global->register, 8-deep double-buffer. LDS 10.2 KB total.
// MODE 0: C = A@B + bias. MODE 2: C = normalize(tanh(A@B + pre_row)).
#define FMA24(a2, b4)                                                       \
    do {                                                                    \
        acc[0][0] += (a2).x * (b4).x; acc[0][1] += (a2).x * (b4).y;         \
        acc[0][2] += (a2).x * (b4).z; acc[0][3] += (a2).x * (b4).w;         \
        acc[1][0] += (a2).y * (b4).x; acc[1][1] += (a2).y * (b4).y;         \
        acc[1][2] += (a2).y * (b4).z; acc[1][3] += (a2).y * (b4).w;         \
    } while (0)

template <int MODE>
__device__ __forceinline__ void gemm8_body(char* smem, int row0,
                                           const float* __restrict__ A,
                                           const int* __restrict__ rowidx,
                                           const float* __restrict__ B,
                                           const float* __restrict__ bias,
                                           const float* __restrict__ pre,
                                           float* __restrict__ Cout) {
    float* sA = (float*)smem;
    const int t = threadIdx.x;
    const int w = t >> 6, l = t & 63;
    const int col4 = l * 4;

    // stage A transposed: thread t -> row r=t&7, k0=(t>>3)*8 (two float4)
    {
        const int r = t & 7, k0 = (t >> 3) << 3;
        const size_t arow = (size_t)(rowidx ? rowidx[row0 + r] : (row0 + r)) * 256;
        const float4 v0 = *reinterpret_cast<const float4*>(&A[arow + k0]);
        const float4 v1 = *reinterpret_cast<const float4*>(&A[arow + k0 + 4]);
        sA[(k0 + 0) * 10 + r] = v0.x; sA[(k0 + 1) * 10 + r] = v0.y;
        sA[(k0 + 2) * 10 + r] = v0.z; sA[(k0 + 3) * 10 + r] = v0.w;
        sA[(k0 + 4) * 10 + r] = v1.x; sA[(k0 + 5) * 10 + r] = v1.y;
        sA[(k0 + 6) * 10 + r] = v1.z; sA[(k0 + 7) * 10 + r] = v1.w;
    }
    __syncthreads();

    float acc[2][4] = {};
    const float* Bp = B + col4;
    float4 bufA[8], bufB[8];
#pragma unroll
    for (int j = 0; j < 8; ++j)
        bufA[j] = *reinterpret_cast<const float4*>(&Bp[(size_t)j * 256]);
    for (int kb = 0; kb < 256; kb += 16) {
#pragma unroll
        for (int j = 0; j < 8; ++j)
            bufB[j] = *reinterpret_cast<const float4*>(&Bp[(size_t)(kb + 8 + j) * 256]);
#pragma unroll
        for (int j = 0; j < 8; ++j) {
            const float2 a2 = *reinterpret_cast<const float2*>(&sA[(kb + j) * 10 + w * 2]);
            FMA24(a2, bufA[j]);
        }
        if (kb + 16 < 256) {
#pragma unroll
            for (int j = 0; j < 8; ++j)
                bufA[j] = *reinterpret_cast<const float4*>(&Bp[(size_t)(kb + 16 + j) * 256]);
        }
#pragma unroll
        for (int j = 0; j < 8; ++j) {
            const float2 a2 = *reinterpret_cast<const float2*>(&sA[(kb + 8 + j) * 10 + w * 2]);
            FMA24(a2, bufB[j]);
        }
    }

#pragma unroll
    for (int i = 0; i < 2; ++i) {
        const int row = row0 + w * 2 + i;
        if (MODE == 0) {
            const float4 b4 = *reinterpret_cast<const float4*>(&bias[col4]);
            *reinterpret_cast<float4*>(&Cout[(size_t)row * 256 + col4]) =
                make_float4(acc[i][0] + b4.x, acc[i][1] + b4.y,
                            acc[i][2] + b4.z, acc[i][3] + b4.w);
        } else {
            const float4 p4 = *reinterpret_cast<const float4*>(&pre[(size_t)row * 256 + col4]);
            const float v0 = tanhf(acc[i][0] + p4.x);
            const float v1 = tanhf(acc[i][1] + p4.y);
            const float v2 = tanhf(acc[i][2] + p4.z);
            const float v3 = tanhf(acc[i][3] + p4.w);
            float sq = v0 * v0 + v1 * v1 + v2 * v2 + v3 * v3;
#pragma unroll
            for (int off = 32; off; off >>= 1) sq += __shfl_xor(sq, off);
            const float invn = 1.0f / fmaxf(sqrtf(sq), 1e-12f);
            *reinterpret_cast<float4*>(&Cout[(size_t)row * 256 + col4]) =
                make_float4(v0 * invn, v1 * invn, v2 * invn, v3 * invn);
        }
    }
}

// ---------------- kernel A: qk-GEMM blocks || mean-gather blocks -----------
__global__ __launch_bounds__(256) void qk_mean(const float* __restrict__ id2feat,
                                               const int* __restrict__ nodes,
                                               const int* __restrict__ neigh_mean,
                                               const float* __restrict__ Wqk,
                                               const float* __restrict__ bqk,
                                               float* __restrict__ Qk,
                                               float* __restrict__ AFmean,
                                               int nqk) {
    __shared__ __align__(16) char smem[10560];
    const int bid = blockIdx.x;
    const int t = threadIdx.x;
    const int w = t >> 6, l = t & 63;
    if (bid < nqk) {
        gemm8_body<0>(smem, bid * 8, id2feat, nodes, Wqk, bqk, nullptr, Qk);
    } else {
        const int b = bid - nqk;
        float4* sRed = (float4*)smem;  // [4][64]
        const float4* f4 = reinterpret_cast<const float4*>(id2feat);
        const int* im = neigh_mean + (size_t)b * S_NEI + w * 8;
        float4 macc = make_float4(0.f, 0.f, 0.f, 0.f);
#pragma unroll
        for (int j = 0; j < 8; ++j) {
            const float4 v = f4[(size_t)im[j] * 64 + l];
            macc.x += v.x; macc.y += v.y; macc.z += v.z; macc.w += v.w;
        }
        sRed[w * 64 + l] = macc;
        __syncthreads();
        if (t < 64) {
            const float4 a0 = sRed[t], a1 = sRed[64 + t], a2 = sRed[128 + t], a3 = sRed[192 + t];
            const float sc = 1.0f / S_NEI;
            reinterpret_cast<float4*>(AFmean + (size_t)b * 256)[t] =
                make_float4((a0.x + a1.x + a2.x + a3.x) * sc,
                            (a0.y + a1.y + a2.y + a3.y) * sc,
                            (a0.z + a1.z + a2.z + a3.z) * sc,
                            (a0.w + a1.w + a2.w + a3.w) * sc);
        }
    }
}

// ---------------- kernel B: pre-GEMM blocks || attn-gather blocks ----------
__global__ __launch_bounds__(256) void attn_pre(const float* __restrict__ id2feat,
                                                const int* __restrict__ neigh_attn,
                                                const float* __restrict__ Qk,
                                                const float* __restrict__ AFmean,
                                                const float* __restrict__ Wmc,
                                                const float* __restrict__ bfull,
                                                float* __restrict__ AFmix,
                                                float* __restrict__ pre,
                                                int nqk) {
    __shared__ __align__(16) char smem[10560];
    const int bid = blockIdx.x;
    const int t = threadIdx.x;
    const int w = t >> 6, l = t & 63;
    if (bid < nqk) {
        gemm8_body<0>(smem, bid * 8, AFmean, nullptr, Wmc, bfull, nullptr, pre);
    } else {
        const int b = bid - nqk;
        float4* sRed = (float4*)smem;              // [4][64] = 4 KB
        float* sS = (float*)(smem + 4096);         // [32]
        const float4* f4 = reinterpret_cast<const float4*>(id2feat);
        const int* ia = neigh_attn + (size_t)b * S_NEI + w * 8;
        float4 r[8];
#pragma unroll
        for (int j = 0; j < 8; ++j) r[j] = f4[(size_t)ia[j] * 64 + l];
        const float4 q = reinterpret_cast<const float4*>(Qk + (size_t)b * 256)[l];
#pragma unroll
        for (int j = 0; j < 8; ++j) {
            float p = q.x * r[j].x + q.y * r[j].y + q.z * r[j].z + q.w * r[j].w;
#pragma unroll
            for (int off = 32; off; off >>= 1) p += __shfl_xor(p, off);
            if (l == 0) sS[w * 8 + j] = p;
        }
        __syncthreads();
        float m = -1e30f;
#pragma unroll
        for (int s = 0; s < S_NEI; ++s) m = fmaxf(m, sS[s]);
        float sum = 0.f;
#pragma unroll
        for (int s = 0; s < S_NEI; ++s) sum += __expf(sS[s] - m);
        const float inv = 1.0f / sum;
        float4 wa = make_float4(0.f, 0.f, 0.f, 0.f);
#pragma unroll
        for (int j = 0; j < 8; ++j) {
            const float g = __expf(sS[w * 8 + j] - m);
            wa.x += g * r[j].x; wa.y += g * r[j].y;
            wa.z += g * r[j].z; wa.w += g * r[j].w;
        }
        sRed[w * 64 + l] = wa;
        __syncthreads();
        if (t < 64) {
            const float4 a0 = sRed[t], a1 = sRed[64 + t], a2 = sRed[128 + t], a3 = sRed[192 + t];
            reinterpret_cast<float4*>(AFmix + (size_t)b * 256)[t] =
                make_float4((a0.x + a1.x + a2.x + a3.x) * inv,
                            (a0.y + a1.y + a2.y + a3.y) * inv,
                            (a0.z + a1.z + a2.z + a3.z) * inv,
                            (a0.w + a1.w + a2.w + a3.w) * inv);
        }
    }
}

// ---------------- kernel C: out = normalize(tanh(mix@Wvc + pre)) -----------
__global__ __launch_bounds__(256) void final8(const float* __restrict__ AFmix,
                                              const float* __restrict__ Wvc,
                                              const float* __restrict__ pre,
                                              float* __restrict__ out) {
    __shared__ __align__(16) char smem[10560];
    gemm8_body<2>(smem, blockIdx.x * 8, AFmix, nullptr, Wvc, nullptr, pre, out);
}

extern "C" void kernel_launch(void* const* d_in, const int* in_sizes, int n_in,
                              void* d_out, int out_size, void* d_ws, size_t ws_size,
                              hipStream_t stream) {
    const int* nodes      = (const int*)d_in[0];
    const int* neigh_mean = (const int*)d_in[1];
    const int* neigh_attn = (const int*)d_in[2];
    const float* id2feat  = (const float*)d_in[3];
    const float* Wm = (const float*)d_in[4];
    const float* bm = (const float*)d_in[5];
    const float* Wq = (const float*)d_in[6];
    const float* bq = (const float*)d_in[7];
    const float* Wk = (const float*)d_in[8];
    // d_in[9] = bk: cancels in softmax
    const float* Wv = (const float*)d_in[10];
    const float* bv = (const float*)d_in[11];
    const float* Wc = (const float*)d_in[12];
    const float* bc = (const float*)d_in[13];
    float* out = (float*)d_out;

    const int B = in_sizes[0];  // 4096
    const int nqk = B / 8;      // 512

    float* ws     = (float*)d_ws;
    float* WkT    = ws;                     // 65536
    float* Wqk    = ws + 65536;             // 65536
    float* Wvc    = ws + 131072;            // 65536
    float* Wmc    = ws + 196608;            // 65536
    float* bqk    = ws + 262144;            // 256
    float* bfull  = ws + 262400;            // 256
    float* Qk     = ws + 262656;            // B*256
    float* AFmean = Qk + (size_t)B * 256;   // B*256
    float* AFmix  = AFmean + (size_t)B * 256;  // B*256
    float* pre    = AFmix + (size_t)B * 256;   // B*256

    transpose256<<<dim3(8, 8), dim3(32, 8), 0, stream>>>(Wk, WkT);
    precompute3<<<dim3(32, 3), 256, 0, stream>>>(Wq, Wv, Wm, Wc, WkT, Wqk, Wvc, Wmc);
    bias_k<<<256, 256, 0, stream>>>(bq, bv, bm, bc, Wc, WkT, bqk, bfull);
    qk_mean<<<nqk + B, 256, 0, stream>>>(id2feat, nodes, neigh_mean, Wqk, bqk,
                                         Qk, AFmean, nqk);
    attn_pre<<<nqk + B, 256, 0, stream>>>(id2feat, neigh_attn, Qk, AFmean, Wmc,
                                          bfull, AFmix, pre, nqk);
    final8<<<nqk, 256, 0, stream>>>(AFmix, Wvc, pre, out);
}

// Round 15
// 78.506 us; speedup vs baseline: 1.4623x; 1.4623x over previous
//
#include <hip/hip_runtime.h>
#include <hip/hip_fp16.h>
#include <math.h>

#define S_NEI 32

// ---------------- transpose 256x256 (WkT[e][f] = Wk[f][e]) ----------------
__global__ __launch_bounds__(256) void transpose256(const float* __restrict__ in,
                                                    float* __restrict__ outT) {
    __shared__ float tile[32][33];
    const int bx = blockIdx.x * 32, by = blockIdx.y * 32;
    const int x = threadIdx.x, y = threadIdx.y;  // 32 x 8
#pragma unroll
    for (int i = 0; i < 32; i += 8)
        tile[y + i][x] = in[(by + y + i) * 256 + bx + x];
    __syncthreads();
#pragma unroll
    for (int i = 0; i < 32; i += 8)
        outT[(bx + y + i) * 256 + by + x] = tile[x][y + i];
}

// ---------------- legacy 8x256 tile GEMM (for tiny precompute GEMMs) -------
template <int KT>
__device__ __forceinline__ void gemm_tile8(const float* __restrict__ A, int row0,
                                           const float* __restrict__ B,
                                           float acc[2][4], float* __restrict__ sA,
                                           float* __restrict__ sB) {
    const int t = threadIdx.x;
    const int tr = t >> 6, tc = t & 63;
    const int r = t >> 5;
    const int k1 = t & 31;
    const size_t arow = (size_t)(row0 + r) * KT;
    for (int kb = 0; kb < KT; kb += 32) {
        sA[k1 * 12 + r] = A[arow + kb + k1];
#pragma unroll
        for (int i = 0; i < 8; ++i) {
            *reinterpret_cast<float4*>(&sB[(i * 4 + tr) * 256 + tc * 4]) =
                *reinterpret_cast<const float4*>(&B[(size_t)(kb + i * 4 + tr) * 256 + tc * 4]);
        }
        __syncthreads();
#pragma unroll
        for (int k = 0; k < 32; ++k) {
            const float2 a2 = *reinterpret_cast<const float2*>(&sA[k * 12 + tr * 2]);
            const float4 b4 = *reinterpret_cast<const float4*>(&sB[k * 256 + tc * 4]);
            acc[0][0] += a2.x * b4.x; acc[0][1] += a2.x * b4.y;
            acc[0][2] += a2.x * b4.z; acc[0][3] += a2.x * b4.w;
            acc[1][0] += a2.y * b4.x; acc[1][1] += a2.y * b4.y;
            acc[1][2] += a2.y * b4.z; acc[1][3] += a2.y * b4.w;
        }
        __syncthreads();
    }
}

// Wqk=Wq@WkT, Wvc=Wv@Wc_top, Wmc=Wm@Wc_bot — OUTPUT IN FP16
__global__ __launch_bounds__(256) void precompute3(const float* __restrict__ Wq,
                                                   const float* __restrict__ Wv,
                                                   const float* __restrict__ Wm,
                                                   const float* __restrict__ Wc,
                                                   const float* __restrict__ WkT,
                                                   __half* __restrict__ Wqk,
                                                   __half* __restrict__ Wfused) {
    __shared__ float sA[32 * 12];
    __shared__ float sB[32 * 256];
    float acc[2][4] = {};
    const float *Ap, *Bp;
    __half* Cp;
    switch (blockIdx.y) {
        case 0: Ap = Wq; Bp = WkT; Cp = Wqk; break;
        case 1: Ap = Wv; Bp = Wc; Cp = Wfused; break;                    // rows 0..255
        default: Ap = Wm; Bp = Wc + 256 * 256; Cp = Wfused + 256 * 256; break;  // rows 256..511
    }
    const int row0 = blockIdx.x * 8;
    gemm_tile8<256>(Ap, row0, Bp, acc, sA, sB);
    const int tr = threadIdx.x >> 6, tc = threadIdx.x & 63;
#pragma unroll
    for (int i = 0; i < 2; ++i) {
        const __half2 h0 = __floats2half2_rn(acc[i][0], acc[i][1]);
        const __half2 h1 = __floats2half2_rn(acc[i][2], acc[i][3]);
        __half2* dst = reinterpret_cast<__half2*>(&Cp[(size_t)(row0 + tr * 2 + i) * 256 + tc * 4]);
        dst[0] = h0;
        dst[1] = h1;
    }
}

// bqk = bq@WkT ; bfull = bv@Wc_top + bm@Wc_bot + bc  (block per column)
__global__ __launch_bounds__(256) void bias_k(const float* __restrict__ bq,
                                              const float* __restrict__ bv,
                                              const float* __restrict__ bm,
                                              const float* __restrict__ bc,
                                              const float* __restrict__ Wc,
                                              const float* __restrict__ WkT,
                                              float* __restrict__ bqk,
                                              float* __restrict__ bfull) {
    const int c = blockIdx.x;
    const int e = threadIdx.x;
    const int w = e >> 6, l = e & 63;
    float a = bq[e] * WkT[e * 256 + c];
    float v = bv[e] * Wc[e * 256 + c] + bm[e] * Wc[(256 + e) * 256 + c];
    __shared__ float redA[4], redV[4];
#pragma unroll
    for (int off = 32; off; off >>= 1) { a += __shfl_xor(a, off); v += __shfl_xor(v, off); }
    if (l == 0) { redA[w] = a; redV[w] = v; }
    __syncthreads();
    if (e == 0) {
        bqk[c] = redA[0] + redA[1] + redA[2] + redA[3];
        bfull[c] = bc[c] + redV[0] + redV[1] + redV[2] + redV[3];
    }
}

// ---------------- fused per-4-node megakernel (R9 base, fp16 B-streams) ----
// Wave w = K-quarter AND owns node b=w. Lane owns 4 cols.
// Phase 1: Qk = self(4x256)@Wqk_h + bqk
// Phase 2: attn+mean, 1 node/wave, online-softmax 8-row chunks
// Phase 3: out = normalize(tanh(AF(4x512)@Wfused_h + bfull))
// B streamed as fp16 (8 B per 4 cols): halves L2 weight traffic (786->393 MB)
// __launch_bounds__(256,2): min-waves>=4 forces 64-VGPR spill (R7/R8).

#define SAF4(k) ((k) * 4 + ((((k) >> 3)) << 2))

#define FMA44(a4, b4)                                                       \
    do {                                                                    \
        acc[0][0] += (a4).x * (b4).x; acc[0][1] += (a4).x * (b4).y;         \
        acc[0][2] += (a4).x * (b4).z; acc[0][3] += (a4).x * (b4).w;         \
        acc[1][0] += (a4).y * (b4).x; acc[1][1] += (a4).y * (b4).y;         \
        acc[1][2] += (a4).y * (b4).z; acc[1][3] += (a4).y * (b4).w;         \
        acc[2][0] += (a4).z * (b4).x; acc[2][1] += (a4).z * (b4).y;         \
        acc[2][2] += (a4).z * (b4).z; acc[2][3] += (a4).z * (b4).w;         \
        acc[3][0] += (a4).w * (b4).x; acc[3][1] += (a4).w * (b4).y;         \
        acc[3][2] += (a4).w * (b4).z; acc[3][3] += (a4).w * (b4).w;         \
    } while (0)

__device__ __forceinline__ float4 h4_to_f4(float2 raw) {
    const __half2* h = reinterpret_cast<const __half2*>(&raw);
    const float2 f0 = __half22float2(h[0]);
    const float2 f1 = __half22float2(h[1]);
    return make_float4(f0.x, f0.y, f1.x, f1.y);
}

__global__ __launch_bounds__(256, 2) void fused4(const float* __restrict__ id2feat,
                                                 const int* __restrict__ nodes,
                                                 const int* __restrict__ neigh_mean,
                                                 const int* __restrict__ neigh_attn,
                                                 const __half* __restrict__ Wqk,
                                                 const float* __restrict__ bqk,
                                                 const __half* __restrict__ Wfused,
                                                 const float* __restrict__ bfull,
                                                 float* __restrict__ out) {
    __shared__ __align__(16) char smem[18112];
    float* R0  = (float*)smem;               // 3120 floats: sA / sP / sAF aliased
    float* sQk = (float*)(smem + 12480);     // 1040 floats
    int*   sIA = (int*)(smem + 16640);       // 128
    int*   sIM = (int*)(smem + 17152);       // 128

    const int t = threadIdx.x;   // 256
    const int w = t >> 6, l = t & 63;
    const int kq = w;
    const int col4 = l * 4;
    const int row0 = blockIdx.x * 4;

    if (t < 128) sIA[t] = neigh_attn[(size_t)row0 * S_NEI + t];
    else sIM[t - 128] = neigh_mean[(size_t)row0 * S_NEI + (t - 128)];

    // stage 4 self rows transposed: wave w reads row w coalesced
    {
        const float4 v = *reinterpret_cast<const float4*>(
            &id2feat[(size_t)nodes[row0 + w] * 256 + col4]);
        R0[SAF4(col4 + 0) + w] = v.x;
        R0[SAF4(col4 + 1) + w] = v.y;
        R0[SAF4(col4 + 2) + w] = v.z;
        R0[SAF4(col4 + 3) + w] = v.w;
    }
    __syncthreads();

    float acc[4][4] = {};

    // ---- phase 1: K-quarter [kq*64, +64), all 256 cols (fp16 B) ----
    {
        const __half* Bp = Wqk + (size_t)(kq * 64) * 256 + col4;
        float2 bufA[8], bufB[8];
#pragma unroll
        for (int j = 0; j < 8; ++j)
            bufA[j] = *reinterpret_cast<const float2*>(&Bp[(size_t)j * 256]);
        for (int kb = 0; kb < 64; kb += 16) {
#pragma unroll
            for (int j = 0; j < 8; ++j)
                bufB[j] = *reinterpret_cast<const float2*>(&Bp[(size_t)(kb + 8 + j) * 256]);
#pragma unroll
            for (int j = 0; j < 8; ++j) {
                const float4 a4 = *reinterpret_cast<const float4*>(&R0[SAF4(kq * 64 + kb + j)]);
                const float4 b4 = h4_to_f4(bufA[j]);
                FMA44(a4, b4);
            }
            if (kb + 16 < 64) {
#pragma unroll
                for (int j = 0; j < 8; ++j)
                    bufA[j] = *reinterpret_cast<const float2*>(&Bp[(size_t)(kb + 16 + j) * 256]);
            }
#pragma unroll
            for (int j = 0; j < 8; ++j) {
                const float4 a4 =
                    *reinterpret_cast<const float4*>(&R0[SAF4(kq * 64 + kb + 8 + j)]);
                const float4 b4 = h4_to_f4(bufB[j]);
                FMA44(a4, b4);
            }
        }
    }
    __syncthreads();  // sA dead
    if (kq) {
        float* p = R0 + ((kq - 1) * 4) * 260 + col4;
#pragma unroll
        for (int r = 0; r < 4; ++r) {
            p[r * 260 + 0] = acc[r][0]; p[r * 260 + 1] = acc[r][1];
            p[r * 260 + 2] = acc[r][2]; p[r * 260 + 3] = acc[r][3];
        }
    }
    __syncthreads();
    if (kq == 0) {
        const float4 bq4 = *reinterpret_cast<const float4*>(&bqk[col4]);
#pragma unroll
        for (int r = 0; r < 4; ++r) {
            float v0 = acc[r][0] + bq4.x, v1 = acc[r][1] + bq4.y;
            float v2 = acc[r][2] + bq4.z, v3 = acc[r][3] + bq4.w;
#pragma unroll
            for (int s = 0; s < 3; ++s) {
                const float* p = R0 + (s * 4 + r) * 260 + col4;
                v0 += p[0]; v1 += p[1]; v2 += p[2]; v3 += p[3];
            }
            sQk[r * 260 + col4 + 0] = v0; sQk[r * 260 + col4 + 1] = v1;
            sQk[r * 260 + col4 + 2] = v2; sQk[r * 260 + col4 + 3] = v3;
        }
    }
    __syncthreads();  // sQk ready, sP dead

    // ---- phase 2: wave w owns node b=w; online softmax in 8-row chunks ----
    {
        const int b = w;
        const float4 q = *reinterpret_cast<const float4*>(&sQk[b * 260 + col4]);
        const float4* f4 = reinterpret_cast<const float4*>(id2feat);
        const int* ia = sIA + b * 32;
        const int* im = sIM + b * 32;
        float4 macc = make_float4(0.f, 0.f, 0.f, 0.f);
        float4 wa = make_float4(0.f, 0.f, 0.f, 0.f);
        float m = -1e30f, e = 0.f;
#pragma unroll
        for (int cch = 0; cch < 4; ++cch) {
            float4 r[8];
#pragma unroll
            for (int j = 0; j < 8; ++j) r[j] = f4[(size_t)ia[cch * 8 + j] * 64 + l];
#pragma unroll
            for (int j = 0; j < 8; ++j) {
                const float4 v = f4[(size_t)im[cch * 8 + j] * 64 + l];
                macc.x += v.x; macc.y += v.y; macc.z += v.z; macc.w += v.w;
            }
            float p[8];
#pragma unroll
            for (int j = 0; j < 8; ++j) {
                float s = q.x * r[j].x + q.y * r[j].y + q.z * r[j].z + q.w * r[j].w;
#pragma unroll
                for (int off = 32; off; off >>= 1) s += __shfl_xor(s, off);
                p[j] = s;
            }
            float cm = p[0];
#pragma unroll
            for (int j = 1; j < 8; ++j) cm = fmaxf(cm, p[j]);
            const float newm = fmaxf(m, cm);
            const float sc = __expf(m - newm);
            e *= sc; wa.x *= sc; wa.y *= sc; wa.z *= sc; wa.w *= sc;
#pragma unroll
            for (int j = 0; j < 8; ++j) {
                const float g = __expf(p[j] - newm);
                e += g;
                wa.x += g * r[j].x; wa.y += g * r[j].y;
                wa.z += g * r[j].z; wa.w += g * r[j].w;
            }
            m = newm;
        }
        const float inv = 1.0f / e;
        const float mixv[4] = {wa.x * inv, wa.y * inv, wa.z * inv, wa.w * inv};
        const float mev[4] = {macc.x * (1.f / 32), macc.y * (1.f / 32),
                              macc.z * (1.f / 32), macc.w * (1.f / 32)};
        // AF transposed: mix -> cols [0,256), mean -> cols [256,512)
#pragma unroll
        for (int c = 0; c < 4; ++c) {
            R0[SAF4(col4 + c) + b] = mixv[c];
            R0[SAF4(256 + col4 + c) + b] = mev[c];
        }
    }
    __syncthreads();  // sAF ready

    // ---- phase 3: K-quarter [kq*128, +128) of AF(4x512)@Wfused (fp16 B) ----
#pragma unroll
    for (int r = 0; r < 4; ++r)
#pragma unroll
        for (int c = 0; c < 4; ++c) acc[r][c] = 0.f;
    {
        const __half* Bp = Wfused + (size_t)(kq * 128) * 256 + col4;
        float2 bufA[8], bufB[8];
#pragma unroll
        for (int j = 0; j < 8; ++j)
            bufA[j] = *reinterpret_cast<const float2*>(&Bp[(size_t)j * 256]);
        for (int kb = 0; kb < 128; kb += 16) {
#pragma unroll
            for (int j = 0; j < 8; ++j)
                bufB[j] = *reinterpret_cast<const float2*>(&Bp[(size_t)(kb + 8 + j) * 256]);
#pragma unroll
            for (int j = 0; j < 8; ++j) {
                const float4 a4 =
                    *reinterpret_cast<const float4*>(&R0[SAF4(kq * 128 + kb + j)]);
                const float4 b4 = h4_to_f4(bufA[j]);
                FMA44(a4, b4);
            }
            if (kb + 16 < 128) {
#pragma unroll
                for (int j = 0; j < 8; ++j)
                    bufA[j] = *reinterpret_cast<const float2*>(&Bp[(size_t)(kb + 16 + j) * 256]);
            }
#pragma unroll
            for (int j = 0; j < 8; ++j) {
                const float4 a4 =
                    *reinterpret_cast<const float4*>(&R0[SAF4(kq * 128 + kb + 8 + j)]);
                const float4 b4 = h4_to_f4(bufB[j]);
                FMA44(a4, b4);
            }
        }
    }
    __syncthreads();  // sAF dead
    if (kq) {
        float* p = R0 + ((kq - 1) * 4) * 260 + col4;
#pragma unroll
        for (int r = 0; r < 4; ++r) {
            p[r * 260 + 0] = acc[r][0]; p[r * 260 + 1] = acc[r][1];
            p[r * 260 + 2] = acc[r][2]; p[r * 260 + 3] = acc[r][3];
        }
    }
    __syncthreads();
    if (kq == 0) {
        const float4 bf4 = *reinterpret_cast<const float4*>(&bfull[col4]);
#pragma unroll
        for (int r = 0; r < 4; ++r) {
            float v0 = acc[r][0] + bf4.x, v1 = acc[r][1] + bf4.y;
            float v2 = acc[r][2] + bf4.z, v3 = acc[r][3] + bf4.w;
#pragma unroll
            for (int s = 0; s < 3; ++s) {
                const float* p = R0 + (s * 4 + r) * 260 + col4;
                v0 += p[0]; v1 += p[1]; v2 += p[2]; v3 += p[3];
            }
            v0 = tanhf(v0); v1 = tanhf(v1); v2 = tanhf(v2); v3 = tanhf(v3);
            float sq = v0 * v0 + v1 * v1 + v2 * v2 + v3 * v3;
#pragma unroll
            for (int off = 32; off; off >>= 1) sq += __shfl_xor(sq, off);
            const float invn = 1.0f / fmaxf(sqrtf(sq), 1e-12f);
            *reinterpret_cast<float4*>(&out[(size_t)(row0 + r) * 256 + col4]) =
                make_float4(v0 * invn, v1 * invn, v2 * invn, v3 * invn);
        }
    }
}

extern "C" void kernel_launch(void* const* d_in, const int* in_sizes, int n_in,
                              void* d_out, int out_size, void* d_ws, size_t ws_size,
                              hipStream_t stream) {
    const int* nodes      = (const int*)d_in[0];
    const int* neigh_mean = (const int*)d_in[1];
    const int* neigh_attn = (const int*)d_in[2];
    const float* id2feat  = (const float*)d_in[3];
    const float* Wm = (const float*)d_in[4];
    const float* bm = (const float*)d_in[5];
    const float* Wq = (const float*)d_in[6];
    const float* bq = (const float*)d_in[7];
    const float* Wk = (const float*)d_in[8];
    // d_in[9] = bk: cancels in softmax
    const float* Wv = (const float*)d_in[10];
    const float* bv = (const float*)d_in[11];
    const float* Wc = (const float*)d_in[12];
    const float* bc = (const float*)d_in[13];
    float* out = (float*)d_out;

    const int B = in_sizes[0];  // 4096

    float* ws      = (float*)d_ws;
    float* WkT     = ws;                          // 65536 f
    __half* Wqk_h  = (__half*)(ws + 65536);       // 65536 halves (32768 f slots)
    __half* Wfus_h = (__half*)(ws + 98304);       // 131072 halves (65536 f slots)
    float* bqk     = ws + 163840;                 // 256 f
    float* bfull   = ws + 164096;                 // 256 f

    transpose256<<<dim3(8, 8), dim3(32, 8), 0, stream>>>(Wk, WkT);
    precompute3<<<dim3(32, 3), 256, 0, stream>>>(Wq, Wv, Wm, Wc, WkT, Wqk_h, Wfus_h);
    bias_k<<<256, 256, 0, stream>>>(bq, bv, bm, bc, Wc, WkT, bqk, bfull);
    fused4<<<B / 4, 256, 0, stream>>>(id2feat, nodes, neigh_mean, neigh_attn,
                                      Wqk_h, bqk, Wfus_h, bfull, out);
}